// Round 9
// baseline (546.293 us; speedup 1.0000x reference)
//
#include <hip/hip_runtime.h>
#include <hip/hip_bf16.h>

typedef __attribute__((ext_vector_type(8))) short bf16x8;
typedef __attribute__((ext_vector_type(4))) float f32x4;
typedef unsigned short u16;
typedef unsigned int u32;

__device__ __forceinline__ u32 bf16_rne(float f) {
  u32 u = __float_as_uint(f);
  return (u + 0x7FFFu + ((u >> 16) & 1u)) >> 16;
}
__device__ __forceinline__ float bf16_val(u32 b) { return __uint_as_float(b << 16); }

__device__ __forceinline__ void g2l16(const u16* g, u16* l) {
  __builtin_amdgcn_global_load_lds(
      (const __attribute__((address_space(1))) u32*)g,
      (__attribute__((address_space(3))) u32*)l, 16, 0, 0);
}

// ---- DPP rotation reduce within a 16-lane row: VALU pipe, not LDS ----
template <int CTRL>
__device__ __forceinline__ float dppmv(float x) {
  return __int_as_float(
      __builtin_amdgcn_mov_dpp(__float_as_int(x), CTRL, 0xF, 0xF, true));
}
__device__ __forceinline__ float rowsum16(float t) {
  t += dppmv<0x128>(t);   // row_ror:8
  t += dppmv<0x124>(t);   // row_ror:4
  t += dppmv<0x122>(t);   // row_ror:2
  t += dppmv<0x121>(t);   // row_ror:1
  return t;
}
__device__ __forceinline__ float rowmax16(float t) {
  t = fmaxf(t, dppmv<0x128>(t));
  t = fmaxf(t, dppmv<0x124>(t));
  t = fmaxf(t, dppmv<0x122>(t));
  t = fmaxf(t, dppmv<0x121>(t));
  return t;
}

// ---- split fp32 array into bf16 hi/lo (no transpose) ----
__global__ void split_arr(const float* __restrict__ in,
                          u16* __restrict__ hi, u16* __restrict__ lo, int n4) {
  int i = blockIdx.x * 256 + threadIdx.x;
  if (i >= n4) return;
  float4 v = ((const float4*)in)[i];
  u32 h0 = bf16_rne(v.x), h1 = bf16_rne(v.y), h2 = bf16_rne(v.z), h3 = bf16_rne(v.w);
  u32 l0 = bf16_rne(v.x - bf16_val(h0));
  u32 l1 = bf16_rne(v.y - bf16_val(h1));
  u32 l2 = bf16_rne(v.z - bf16_val(h2));
  u32 l3 = bf16_rne(v.w - bf16_val(h3));
  ushort4 hv; hv.x = (u16)h0; hv.y = (u16)h1; hv.z = (u16)h2; hv.w = (u16)h3;
  ushort4 lv; lv.x = (u16)l0; lv.y = (u16)l1; lv.z = (u16)l2; lv.w = (u16)l3;
  ((ushort4*)hi)[i] = hv;
  ((ushort4*)lo)[i] = lv;
}

// ---- transpose each 256x256 fp32 slice and split into bf16 hi/lo arrays ----
__global__ void split_transpose256(const float* __restrict__ in,
                                   u16* __restrict__ hi, u16* __restrict__ lo) {
  __shared__ float tile[32][33];
  const size_t off = (size_t)blockIdx.z * 65536;
  const int tx = threadIdx.x, ty = threadIdx.y;
#pragma unroll
  for (int i = 0; i < 4; ++i) {
    int y = blockIdx.y * 32 + ty + i * 8;
    int x = blockIdx.x * 32 + tx;
    tile[ty + i * 8][tx] = in[off + (size_t)y * 256 + x];
  }
  __syncthreads();
#pragma unroll
  for (int i = 0; i < 4; ++i) {
    float v = tile[tx][ty + i * 8];
    u32 hb = bf16_rne(v);
    u32 lb = bf16_rne(v - bf16_val(hb));
    size_t idx = off + (size_t)(blockIdx.x * 32 + ty + i * 8) * 256 + blockIdx.y * 32 + tx;
    hi[idx] = (u16)hb;
    lo[idx] = (u16)lb;
  }
}

// ---------------- fused priors-GEMM (split-bf16) + dynamic routing ----------------
// ROUND-9: SAME P-STATE, TWICE THE WAVES. Round-8 accounting: 2 waves/SIMD can't
// cover MFMA+VALU+latency (MFMA 43%, VALU 29%, both-idle ~28%). Block = 512 thr
// = 8 waves, grid mg(2) x eg(4), wave tile 64x64 -> acc[4][4] = 64 regs; total
// ~120 regs/wave fits the 128-reg budget of __launch_bounds__(512,4) -> 4
// waves/SIMD, 2 blocks/CU (LDS ~71KB), 16 waves/CU. RF footprint per block
// unchanged (P = 128x256 f32); waves sharing it doubled.
// W: JIT global->VGPR per k-slice (no reg dbuf -- the reg cut that makes 128
// fit). W loads issued BEFORE the A-slice DMA each step, so the compiler's
// W-wait is a counted vmcnt(2) that also retires the A slice needed next step
// (W stays only transiently outstanding; A ring 4x16KB, 2 slices in flight).
// A: global_load_lds, k-granule XOR swizzle (source pre-swizzled, linear LDS
// dest, readers pick slot q ^ ((li>>1)&3)) -- 0 conflicts, proven r4-r8.
// Routing: R=128 adds one smat cross-mg exchange barrier (round-2 pattern);
// R=64 is fully wave-local per mg (each mg = one routing). Scale-folded logits
// (round-8), parity-dbuf wlog/sqpart, all-wave redundant softmax, DPP reduces.
template <int R>
__global__ __launch_bounds__(512, 4) void caps_route(
    const u16* __restrict__ Ahi_g,   // [ab][128 rows][256] bf16-hi
    const u16* __restrict__ Alo_g,
    const u16* __restrict__ Whi,     // [KN][256][256] (transposed [e][d])
    const u16* __restrict__ Wlo,
    u16* __restrict__ o1hi, u16* __restrict__ o1lo,   // stage1 out (split)
    float* __restrict__ outp,                          // stage2 out
    int KN, int stage) {
  constexpr int ABS = (R == 128) ? 6 : 5;   // log2(a-blocks in grid)
  __shared__ __align__(16) u16 Ab[4][8192];        // A ring: 4 x 16KB slices
  __shared__ __align__(16) float smat[2][256];     // R=128 cross-mg s exchange
  __shared__ __align__(16) float wlog[2][4][128];  // iter-parity dbuf
  __shared__ __align__(16) float probs[128];
  __shared__ float sqpart[2][2][4];

  const int tid = threadIdx.x;
  const int w = tid >> 6, lane = tid & 63, q = lane >> 4, li = lane & 15;
  const int mg = w >> 2, eg = w & 3;        // wave grid 2 x 4
  const int kk = blockIdx.x >> ABS;         // weight slice (h or c)
  const int ab = blockIdx.x & ((1 << ABS) - 1);

  // ---- A staging: wave w stages chunk w (16 rows) of hi and lo (2 DMAs/slice) ----
  const int sub = lane >> 2, p2 = lane & 3;
  const int gslot = p2 ^ ((sub >> 1) & 3);             // pre-swizzled k-granule
  const size_t lane_off = (size_t)sub * 256 + gslot * 8;
  const u16* gAh = Ahi_g + (size_t)ab * 32768 + (size_t)w * 4096 + lane_off;
  const u16* gAl = Alo_g + (size_t)ab * 32768 + (size_t)w * 4096 + lane_off;

  auto STAGE = [&](int ko, int slot) {
    u16* d = &Ab[slot][w * 512] + lane * 8;            // linear LDS dest (DMA rule)
    g2l16(gAh + ko, d);
    g2l16(gAl + ko, d + 4096);
  };

  // ---- W fragment global pointers (JIT global->VGPR; shared by both mg) ----
  const u16* gWh = Whi + (size_t)kk * 65536 + (size_t)(eg * 64 + li) * 256 + q * 8;
  const u16* gWl = Wlo + (size_t)kk * 65536 + (size_t)(eg * 64 + li) * 256 + q * 8;

  // ---- A fragment read offset (swizzled slot) ----
  const int rslot = q ^ ((li >> 1) & 3);
  const int fbase = li * 32 + rslot * 8;               // u16 units within a chunk

  f32x4 acc[4][4] = {};

  // prologue: A slices 0,1 -> slots 0,1
  STAGE(0, 0);
  STAGE(32, 1);
  asm volatile("s_waitcnt vmcnt(0)" ::: "memory");
  __builtin_amdgcn_s_barrier();

  // ---- GEMM main loop: P = A (128 x 256) @ W[kk] (256 x 256), split-bf16 3-MFMA ----
#pragma unroll
  for (int ks = 0; ks < 8; ++ks) {
    // W for slice ks (JIT; issued BEFORE the A DMA so the W-wait is counted)
    bf16x8 bh[4], bl[4];
#pragma unroll
    for (int ct = 0; ct < 4; ++ct) {
      bh[ct] = *(const bf16x8*)(gWh + ct * 4096 + ks * 32);
      bl[ct] = *(const bf16x8*)(gWl + ct * 4096 + ks * 32);
    }
    if (ks < 6) STAGE((ks + 2) * 32, (ks + 2) & 3);    // A slice ks+2
    const u16* aB = &Ab[ks & 3][0] + fbase;
#pragma unroll
    for (int mt = 0; mt < 4; ++mt) {
      bf16x8 ah = *(const bf16x8*)(aB + (mg * 4 + mt) * 512);
      bf16x8 al = *(const bf16x8*)(aB + (mg * 4 + mt) * 512 + 4096);
#pragma unroll
      for (int ct = 0; ct < 4; ++ct) {
        acc[mt][ct] = __builtin_amdgcn_mfma_f32_16x16x32_bf16(al, bh[ct], acc[mt][ct], 0, 0, 0);
        acc[mt][ct] = __builtin_amdgcn_mfma_f32_16x16x32_bf16(ah, bl[ct], acc[mt][ct], 0, 0, 0);
        acc[mt][ct] = __builtin_amdgcn_mfma_f32_16x16x32_bf16(ah, bh[ct], acc[mt][ct], 0, 0, 0);
      }
    }
    if (ks < 7) {
      asm volatile("s_waitcnt vmcnt(2)" ::: "memory"); // next slice landed; ks+2 in flight
      __builtin_amdgcn_s_barrier();
    }
  }

  // ---- dynamic routing (3 iterations) ----
  // R=128: one routing over all 8 waves (smat exchange across mg).
  // R=64: routing a = ab*2 + mg, fully wave-local per mg.
  const float invR = 1.0f / R;
  const int rb = mg * 64;
  float v[4];
  float scl = 0.f;
  float lg0 = 0.f, lg1 = 0.f;   // R=128: rows lane/lane+64 (all waves); R=64: lg0 = row rb+lane

  for (int iter = 0; iter < 3; ++iter) {
    const int par = iter & 1;
    float4 p4[4];
    if (iter == 0) {
#pragma unroll
      for (int mt = 0; mt < 4; ++mt) {
        p4[mt].x = invR; p4[mt].y = invR; p4[mt].z = invR; p4[mt].w = invR;
      }
    } else {
#pragma unroll
      for (int mt = 0; mt < 4; ++mt)
        p4[mt] = *(const float4*)&probs[rb + mt * 16 + q * 4];
    }
    // s partial over this wave's 64 rows: in-lane over (mt,rr), shfl over q
    float s[4];
#pragma unroll
    for (int ct = 0; ct < 4; ++ct) {
      float t = 0.f;
#pragma unroll
      for (int mt = 0; mt < 4; ++mt) {
        t += p4[mt].x * acc[mt][ct][0] + p4[mt].y * acc[mt][ct][1] +
             p4[mt].z * acc[mt][ct][2] + p4[mt].w * acc[mt][ct][3];
      }
      t += __shfl_xor(t, 16);
      t += __shfl_xor(t, 32);
      s[ct] = t;
    }
    if (R == 128) {   // cross-mg exchange to full s
      if (q == 0) {
#pragma unroll
        for (int ct = 0; ct < 4; ++ct) smat[mg][eg * 64 + ct * 16 + li] = s[ct];
      }
      __syncthreads();
#pragma unroll
      for (int ct = 0; ct < 4; ++ct) {
        int e = eg * 64 + ct * 16 + li;
        s[ct] = smat[0][e] + smat[1][e];
      }
    }
    // squash partial: sum_e s^2 over this wave's 64 e (DPP); eg exchange via LDS
    float ss = s[0] * s[0] + s[1] * s[1] + s[2] * s[2] + s[3] * s[3];
    ss = rowsum16(ss);
    if (lane == 0) sqpart[par][(R == 128) ? 0 : mg][eg] = ss;
    // logits partials with UNSCALED s (P.v = scale*(P.s); scale applied after)
    if (iter < 2) {
#pragma unroll
      for (int mt = 0; mt < 4; ++mt) {
        float tt[4];
#pragma unroll
        for (int rr = 0; rr < 4; ++rr) {
          float t = acc[mt][0][rr] * s[0] + acc[mt][1][rr] * s[1] +
                    acc[mt][2][rr] * s[2] + acc[mt][3][rr] * s[3];
          tt[rr] = rowsum16(t);
        }
        if (li == 0)
          *(float4*)&wlog[par][eg][rb + mt * 16 + q * 4] =
              make_float4(tt[0], tt[1], tt[2], tt[3]);
      }
    }
    __syncthreads();
    {
      const int sgi = (R == 128) ? 0 : mg;
      float sq = sqpart[par][sgi][0] + sqpart[par][sgi][1] +
                 sqpart[par][sgi][2] + sqpart[par][sgi][3];
      scl = (sq > 0.f) ? sq / ((1.0f + sq) * sqrtf(sq)) : 0.f;
#pragma unroll
      for (int ct = 0; ct < 4; ++ct) v[ct] = s[ct] * scl;
    }

    if (iter < 2) {
      if (R == 128) {
        // all-wave redundant softmax over 128 rows
        int r0 = lane, r1 = lane + 64;
        float d0 = wlog[par][0][r0] + wlog[par][1][r0] + wlog[par][2][r0] + wlog[par][3][r0];
        float d1 = wlog[par][0][r1] + wlog[par][1][r1] + wlog[par][2][r1] + wlog[par][3][r1];
        lg0 += scl * d0;
        lg1 += scl * d1;
        float m = fmaxf(lg0, lg1);
        m = rowmax16(m);
        m = fmaxf(m, __shfl_xor(m, 16));
        m = fmaxf(m, __shfl_xor(m, 32));
        float e0 = __expf(lg0 - m), e1 = __expf(lg1 - m);
        float zz = e0 + e1;
        zz = rowsum16(zz);
        zz += __shfl_xor(zz, 16);
        zz += __shfl_xor(zz, 32);
        float inv = 1.0f / zz;
        probs[r0] = e0 * inv;
        probs[r1] = e1 * inv;
      } else {
        // wave-local softmax over this mg's 64 rows (eg waves redundant)
        int r0 = rb + lane;
        float d0 = wlog[par][0][r0] + wlog[par][1][r0] + wlog[par][2][r0] + wlog[par][3][r0];
        lg0 += scl * d0;
        float m = rowmax16(lg0);
        m = fmaxf(m, __shfl_xor(m, 16));
        m = fmaxf(m, __shfl_xor(m, 32));
        float e0 = __expf(lg0 - m);
        float z = rowsum16(e0);
        z += __shfl_xor(z, 16);
        z += __shfl_xor(z, 32);
        probs[r0] = e0 / z;
      }
      asm volatile("s_waitcnt lgkmcnt(0)" ::: "memory");  // own writes land before next-iter reads
    }
  }

  // ---- epilogue. stage1 -> split out1[a][kk][e]; stage2 -> fp32 out[kk][a][e] ----
  if (q == 0 && (R == 64 || mg == 0)) {
    const int ag = (R == 128) ? ab : (ab * 2 + mg);    // global a
    if (stage == 1) {
      size_t ob = ((size_t)ag * KN + kk) * 256;
#pragma unroll
      for (int ct = 0; ct < 4; ++ct) {
        int e = eg * 64 + ct * 16 + li;
        u32 hb = bf16_rne(v[ct]);
        u32 lb = bf16_rne(v[ct] - bf16_val(hb));
        o1hi[ob + e] = (u16)hb;
        o1lo[ob + e] = (u16)lb;
      }
    } else {
      size_t ob = ((size_t)kk * 64 + ag) * 256;
#pragma unroll
      for (int ct = 0; ct < 4; ++ct) {
        int e = eg * 64 + ct * 16 + li;
        outp[ob + e] = v[ct];
      }
    }
  }
}

extern "C" void kernel_launch(void* const* d_in, const int* in_sizes, int n_in,
                              void* d_out, int out_size, void* d_ws, size_t ws_size,
                              hipStream_t stream) {
  const float* x  = (const float*)d_in[0];   // [64][128][256]
  const float* w1 = (const float*)d_in[1];   // [64][256][256]
  const float* wc = (const float*)d_in[2];   // [32][256][256]
  float* out = (float*)d_out;                // [32][64][256]

  char* ws = (char*)d_ws;
  u16* w1hi = (u16*)(ws);                    // 8 MB
  u16* w1lo = (u16*)(ws + (8u << 20));       // 8 MB
  u16* wchi = (u16*)(ws + (16u << 20));      // 4 MB
  u16* wclo = (u16*)(ws + (20u << 20));      // 4 MB
  u16* xhi  = (u16*)(ws + (24u << 20));      // 4 MB
  u16* xlo  = (u16*)(ws + (28u << 20));      // 4 MB
  u16* o1hi = (u16*)(ws + (32u << 20));      // 2 MB
  u16* o1lo = (u16*)(ws + (34u << 20));      // 2 MB

  split_arr<<<2048, 256, 0, stream>>>(x, xhi, xlo, 524288);
  split_transpose256<<<dim3(8, 8, 64), dim3(32, 8), 0, stream>>>(w1, w1hi, w1lo);
  split_transpose256<<<dim3(8, 8, 32), dim3(32, 8), 0, stream>>>(wc, wchi, wclo);
  // stage 1: 64 kk x 64 a-blocks (M=128 = 1 routing of R=128), 8 waves/block
  caps_route<128><<<64 * 64, 512, 0, stream>>>(xhi, xlo, w1hi, w1lo, o1hi, o1lo, nullptr, 64, 1);
  // stage 2: 32 kk x 32 a-pair-blocks (M=128 = 2 routings of R=64), 8 waves/block
  caps_route<64><<<32 * 32, 512, 0, stream>>>(o1hi, o1lo, wchi, wclo, nullptr, nullptr, out, 32, 2);
}

// Round 10
// 361.275 us; speedup vs baseline: 1.5121x; 1.5121x over previous
//
#include <hip/hip_runtime.h>
#include <hip/hip_bf16.h>

typedef __attribute__((ext_vector_type(8))) short bf16x8;
typedef __attribute__((ext_vector_type(16))) float f32x16;
typedef unsigned short u16;
typedef unsigned int u32;

__device__ __forceinline__ u32 bf16_rne(float f) {
  u32 u = __float_as_uint(f);
  return (u + 0x7FFFu + ((u >> 16) & 1u)) >> 16;
}
__device__ __forceinline__ float bf16_val(u32 b) { return __uint_as_float(b << 16); }

__device__ __forceinline__ void g2l16(const u16* g, u16* l) {
  __builtin_amdgcn_global_load_lds(
      (const __attribute__((address_space(1))) u32*)g,
      (__attribute__((address_space(3))) u32*)l, 16, 0, 0);
}

// ---- DPP rotation reduce within a 16-lane row: VALU pipe, not LDS ----
template <int CTRL>
__device__ __forceinline__ float dppmv(float x) {
  return __int_as_float(
      __builtin_amdgcn_mov_dpp(__float_as_int(x), CTRL, 0xF, 0xF, true));
}
__device__ __forceinline__ float rowsum16(float t) {
  t += dppmv<0x128>(t);   // row_ror:8
  t += dppmv<0x124>(t);   // row_ror:4
  t += dppmv<0x122>(t);   // row_ror:2
  t += dppmv<0x121>(t);   // row_ror:1
  return t;
}
__device__ __forceinline__ float rowmax16(float t) {
  t = fmaxf(t, dppmv<0x128>(t));
  t = fmaxf(t, dppmv<0x124>(t));
  t = fmaxf(t, dppmv<0x122>(t));
  t = fmaxf(t, dppmv<0x121>(t));
  return t;
}

// ---- split fp32 array into bf16 hi/lo (no transpose) ----
__global__ void split_arr(const float* __restrict__ in,
                          u16* __restrict__ hi, u16* __restrict__ lo, int n4) {
  int i = blockIdx.x * 256 + threadIdx.x;
  if (i >= n4) return;
  float4 v = ((const float4*)in)[i];
  u32 h0 = bf16_rne(v.x), h1 = bf16_rne(v.y), h2 = bf16_rne(v.z), h3 = bf16_rne(v.w);
  u32 l0 = bf16_rne(v.x - bf16_val(h0));
  u32 l1 = bf16_rne(v.y - bf16_val(h1));
  u32 l2 = bf16_rne(v.z - bf16_val(h2));
  u32 l3 = bf16_rne(v.w - bf16_val(h3));
  ushort4 hv; hv.x = (u16)h0; hv.y = (u16)h1; hv.z = (u16)h2; hv.w = (u16)h3;
  ushort4 lv; lv.x = (u16)l0; lv.y = (u16)l1; lv.z = (u16)l2; lv.w = (u16)l3;
  ((ushort4*)hi)[i] = hv;
  ((ushort4*)lo)[i] = lv;
}

// ---- transpose each 256x256 fp32 slice and split into bf16 hi/lo arrays ----
__global__ void split_transpose256(const float* __restrict__ in,
                                   u16* __restrict__ hi, u16* __restrict__ lo) {
  __shared__ float tile[32][33];
  const size_t off = (size_t)blockIdx.z * 65536;
  const int tx = threadIdx.x, ty = threadIdx.y;
#pragma unroll
  for (int i = 0; i < 4; ++i) {
    int y = blockIdx.y * 32 + ty + i * 8;
    int x = blockIdx.x * 32 + tx;
    tile[ty + i * 8][tx] = in[off + (size_t)y * 256 + x];
  }
  __syncthreads();
#pragma unroll
  for (int i = 0; i < 4; ++i) {
    float v = tile[tx][ty + i * 8];
    u32 hb = bf16_rne(v);
    u32 lb = bf16_rne(v - bf16_val(hb));
    size_t idx = off + (size_t)(blockIdx.x * 32 + ty + i * 8) * 256 + blockIdx.y * 32 + tx;
    hi[idx] = (u16)hb;
    lo[idx] = (u16)lb;
  }
}

// ---------------- fused priors-GEMM (split-bf16) + dynamic routing ----------------
// ROUND-10 = ROUND-8 BASE (best, 335us) + 32x32x16 MFMA SHAPE.
// Same FLOPs in 384 mfma_32x32x16 (8.07cyc) vs 768 mfma_16x16x32 (4.63cyc)
// = -13% matrix-pipe cycles (m119: 2495 vs 2176 TF). Round-9 lesson (3rd spill):
// P-state = 128KB acc/block; 2 blocks/CU = half the RF; 8 waves/CU x 256 regs
// IS the pool -- occupancy is closed, only per-wave efficiency remains.
// M=128/block, 256 thr = 4 waves eg(4), wave tile 128x64 = 4mt(32) x 2ct(32),
// acc[4][2] f32x16 = 128 AGPR. __launch_bounds__(256,2).
// Fragments (K-doubling pattern, anchored by working 16x16x32 kernel):
//   A: row = l&31, k = (l>>5)*8 + j ; B(=W): e = l&31, same k.
//   C/D [m74/m101 verified]: col(e) = lane&31, row(b) = (reg&3)+8*(reg>>2)+4*(lane>>5).
// GEMM: r8 pair-steps (2 slices/barrier), A ring 4x16KB via global_load_lds with
// k-granule XOR swizzle; W global->VGPR prefetch; counted vmcnt(8) at pair end.
// Routing: scale-folded logits (unscaled s before barrier, scale after), DPP
// rowsum16 + 2-partial writes per 16-lane half (no cross-row shfl), iter-parity
// dbuf, all-wave redundant softmax. s-pass needs only ONE shfl (xor32).
template <int R>
__global__ __launch_bounds__(256, 2) void caps_route(
    const u16* __restrict__ Ahi_g,   // [ab][128 rows][256] bf16-hi
    const u16* __restrict__ Alo_g,
    const u16* __restrict__ Whi,     // [KN][256][256] (transposed [e][d])
    const u16* __restrict__ Wlo,
    u16* __restrict__ o1hi, u16* __restrict__ o1lo,   // stage1 out (split)
    float* __restrict__ outp,                          // stage2 out
    int KN, int stage) {
  constexpr int SEG = 128 / R;              // routings per block (1 or 2)
  constexpr int MTS = 4 / SEG;              // 32-row m-tiles per routing
  constexpr int ABS = (R == 128) ? 6 : 5;   // log2(a-blocks in grid)
  __shared__ __align__(16) u16 Ab[4][8192];        // A ring: 4 x 16KB slices
  __shared__ __align__(16) float wlog[2][8][128];  // iter-parity dbuf, 8 partials
  __shared__ __align__(16) float probs[128];
  __shared__ float sqpart[2][2][8];

  const int tid = threadIdx.x;
  const int w = tid >> 6, lane = tid & 63;
  const int li = lane & 15, l31 = lane & 31;
  const int hi = lane >> 5, lh = (lane >> 4) & 1;
  const int eg = w;                         // wave = column group (64 e's)
  const int kk = blockIdx.x >> ABS;         // weight slice (h or c)
  const int ab = blockIdx.x & ((1 << ABS) - 1);

  // ---- A staging: wave w stages chunks {2w, 2w+1} of hi and lo (4 DMAs/slice) ----
  const int sub = lane >> 2, p2 = lane & 3;
  const int gslot = p2 ^ ((sub >> 1) & 3);             // pre-swizzled k-granule
  const size_t lane_off = (size_t)sub * 256 + gslot * 8;
  const u16* gAh = Ahi_g + (size_t)ab * 32768 + (size_t)(2 * w) * 4096 + lane_off;
  const u16* gAl = Alo_g + (size_t)ab * 32768 + (size_t)(2 * w) * 4096 + lane_off;

  auto STAGE = [&](int ko, int slot) {
    u16* d = &Ab[slot][(2 * w) * 512] + lane * 8;      // linear LDS dest (DMA rule)
    g2l16(gAh + ko, d);
    g2l16(gAh + ko + 4096, d + 512);
    g2l16(gAl + ko, d + 4096);
    g2l16(gAl + ko + 4096, d + 4608);
  };

  // ---- W fragment global pointers (global->VGPR; 16B per lane) ----
  // frag (ct,ksub,ks): gW? + ct*8192 + ks*32 + ksub*16 ; e = eg*64+ct*32+l31.
  const u16* gWh = Whi + (size_t)kk * 65536 + (size_t)(eg * 64 + l31) * 256 + hi * 8;
  const u16* gWl = Wlo + (size_t)kk * 65536 + (size_t)(eg * 64 + l31) * 256 + hi * 8;

  // ---- A fragment read offsets (swizzled k-granule), per ksub ----
  const int sw = (li >> 1) & 3;
  const int aoff0 = lh * 512 + li * 32 + ((hi ^ sw) * 8);        // ksub=0
  const int aoff1 = lh * 512 + li * 32 + (((2 + hi) ^ sw) * 8);  // ksub=1

  f32x16 acc[4][2] = {};

#define LOADW(dh, dl, s)                                                \
  do {                                                                  \
    _Pragma("unroll")                                                   \
    for (int ct = 0; ct < 2; ++ct) {                                    \
      _Pragma("unroll")                                                 \
      for (int kb = 0; kb < 2; ++kb) {                                  \
        dh[ct][kb] = *(const bf16x8*)(gWh + ct * 8192 + (s) * 32 + kb * 16); \
        dl[ct][kb] = *(const bf16x8*)(gWl + ct * 8192 + (s) * 32 + kb * 16); \
      }                                                                 \
    }                                                                   \
  } while (0)

#define MFMA_SLICE(slot)                                                      \
  do {                                                                        \
    const u16* aB = &Ab[slot][0];                                             \
    _Pragma("unroll")                                                         \
    for (int mt = 0; mt < 4; ++mt) {                                          \
      bf16x8 ah0 = *(const bf16x8*)(aB + mt * 1024 + aoff0);                  \
      bf16x8 al0 = *(const bf16x8*)(aB + mt * 1024 + aoff0 + 4096);           \
      bf16x8 ah1 = *(const bf16x8*)(aB + mt * 1024 + aoff1);                  \
      bf16x8 al1 = *(const bf16x8*)(aB + mt * 1024 + aoff1 + 4096);           \
      _Pragma("unroll")                                                       \
      for (int ct = 0; ct < 2; ++ct) {                                        \
        acc[mt][ct] = __builtin_amdgcn_mfma_f32_32x32x16_bf16(al0, bh[ct][0], acc[mt][ct], 0, 0, 0); \
        acc[mt][ct] = __builtin_amdgcn_mfma_f32_32x32x16_bf16(ah0, bl[ct][0], acc[mt][ct], 0, 0, 0); \
        acc[mt][ct] = __builtin_amdgcn_mfma_f32_32x32x16_bf16(ah0, bh[ct][0], acc[mt][ct], 0, 0, 0); \
        acc[mt][ct] = __builtin_amdgcn_mfma_f32_32x32x16_bf16(al1, bh[ct][1], acc[mt][ct], 0, 0, 0); \
        acc[mt][ct] = __builtin_amdgcn_mfma_f32_32x32x16_bf16(ah1, bl[ct][1], acc[mt][ct], 0, 0, 0); \
        acc[mt][ct] = __builtin_amdgcn_mfma_f32_32x32x16_bf16(ah1, bh[ct][1], acc[mt][ct], 0, 0, 0); \
      }                                                                       \
    }                                                                         \
  } while (0)

  // prologue: W(0) -> regs; A slices 0,1 -> slots 0,1
  bf16x8 bh[2][2], bl[2][2];
  LOADW(bh, bl, 0);
  STAGE(0, 0);
  STAGE(32, 1);
  asm volatile("s_waitcnt vmcnt(0)" ::: "memory");
  __builtin_amdgcn_s_barrier();

  // ---- GEMM main loop: 4 pair-steps, one sync each (r8 schedule) ----
#pragma unroll
  for (int p = 0; p < 4; ++p) {
    const int s0 = 2 * p, s1 = 2 * p + 1;
    if (p < 3) {                                       // next pair's A DMAs (oldest)
      STAGE((s0 + 2) * 32, (s0 + 2) & 3);
      STAGE((s1 + 2) * 32, (s1 + 2) & 3);
      __builtin_amdgcn_sched_barrier(0);               // pin DMAs before W loads
    }
    bf16x8 nbh[2][2], nbl[2][2];
    LOADW(nbh, nbl, s1);
    MFMA_SLICE(s0 & 3);
#pragma unroll
    for (int ct = 0; ct < 2; ++ct) {
#pragma unroll
      for (int kb = 0; kb < 2; ++kb) { bh[ct][kb] = nbh[ct][kb]; bl[ct][kb] = nbl[ct][kb]; }
    }
    if (p < 3) LOADW(nbh, nbl, s0 + 2);
    MFMA_SLICE(s1 & 3);
    if (p < 3) {
#pragma unroll
      for (int ct = 0; ct < 2; ++ct) {
#pragma unroll
        for (int kb = 0; kb < 2; ++kb) { bh[ct][kb] = nbh[ct][kb]; bl[ct][kb] = nbl[ct][kb]; }
      }
      asm volatile("s_waitcnt vmcnt(8)" ::: "memory"); // A(p+1) drained; W stays in flight
      __builtin_amdgcn_s_barrier();
    }
  }
#undef MFMA_SLICE
#undef LOADW

  // ---- dynamic routing (3 iterations), 1 barrier per iter ----
  // Lane coverage: e = eg*64 + ct*32 + l31 ; rows b = mt*32 + (r&3) + 8*(r>>2) + 4*hi.
  const float invR = 1.0f / R;
  const int hi4 = hi * 4;
  float v[SEG][2];
  float scl[SEG];
  float lg0 = 0.f, lg1 = 0.f;                          // rows lane / lane+64

  for (int iter = 0; iter < 3; ++iter) {
    const int par = iter & 1;
    // s[a][e] = sum_b probs[b]*P[b,e]: in-lane over (mt,reg), ONE shfl (xor32)
    float s[SEG][2];
#pragma unroll
    for (int sg = 0; sg < SEG; ++sg) {
      float t0 = 0.f, t1 = 0.f;
#pragma unroll
      for (int mi = 0; mi < MTS; ++mi) {
        const int mt = sg * MTS + mi;
#pragma unroll
        for (int g = 0; g < 4; ++g) {
          float4 pv;
          if (iter == 0) { pv.x = invR; pv.y = invR; pv.z = invR; pv.w = invR; }
          else           pv = *(const float4*)&probs[mt * 32 + g * 8 + hi4];
          t0 += pv.x * acc[mt][0][4 * g + 0] + pv.y * acc[mt][0][4 * g + 1] +
                pv.z * acc[mt][0][4 * g + 2] + pv.w * acc[mt][0][4 * g + 3];
          t1 += pv.x * acc[mt][1][4 * g + 0] + pv.y * acc[mt][1][4 * g + 1] +
                pv.z * acc[mt][1][4 * g + 2] + pv.w * acc[mt][1][4 * g + 3];
        }
      }
      t0 += __shfl_xor(t0, 32);
      t1 += __shfl_xor(t1, 32);
      s[sg][0] = t0; s[sg][1] = t1;
    }
    // squash partials: rowsum16 then 2 partials per wave (lh halves), sum-8 after barrier
#pragma unroll
    for (int sg = 0; sg < SEG; ++sg) {
      float ss = s[sg][0] * s[sg][0] + s[sg][1] * s[sg][1];
      ss = rowsum16(ss);
      if (li == 0 && hi == 0) sqpart[par][sg][eg * 2 + lh] = ss;
    }
    // logits partials with UNSCALED s (P.v = scale*(P.s); scale applied after)
    if (iter < 2) {
#pragma unroll
      for (int mt = 0; mt < 4; ++mt) {
        const int sg = mt / MTS;
#pragma unroll
        for (int g = 0; g < 4; ++g) {
          float tt0, tt1, tt2, tt3;
          { float t = acc[mt][0][4*g+0] * s[sg][0] + acc[mt][1][4*g+0] * s[sg][1]; tt0 = rowsum16(t); }
          { float t = acc[mt][0][4*g+1] * s[sg][0] + acc[mt][1][4*g+1] * s[sg][1]; tt1 = rowsum16(t); }
          { float t = acc[mt][0][4*g+2] * s[sg][0] + acc[mt][1][4*g+2] * s[sg][1]; tt2 = rowsum16(t); }
          { float t = acc[mt][0][4*g+3] * s[sg][0] + acc[mt][1][4*g+3] * s[sg][1]; tt3 = rowsum16(t); }
          if (li == 0)
            *(float4*)&wlog[par][eg * 2 + lh][mt * 32 + g * 8 + hi4] =
                make_float4(tt0, tt1, tt2, tt3);
        }
      }
    }
    __syncthreads();                                   // the ONE barrier per iter
    // scale from squash (sum 8 partials, broadcast reads)
#pragma unroll
    for (int sg = 0; sg < SEG; ++sg) {
      float sq = 0.f;
#pragma unroll
      for (int j = 0; j < 8; ++j) sq += sqpart[par][sg][j];
      scl[sg] = (sq > 0.f) ? sq / ((1.0f + sq) * sqrtf(sq)) : 0.f;
      v[sg][0] = s[sg][0] * scl[sg];
      v[sg][1] = s[sg][1] * scl[sg];
    }

    if (iter < 2) {
      // all-wave redundant softmax; logits += scale * sum of 8 wlog partials
      int r0 = lane, r1 = lane + 64;
      float d0 = 0.f, d1 = 0.f;
#pragma unroll
      for (int j = 0; j < 8; ++j) { d0 += wlog[par][j][r0]; d1 += wlog[par][j][r1]; }
      if (R == 128) {
        lg0 += scl[0] * d0;
        lg1 += scl[0] * d1;
        float m = fmaxf(lg0, lg1);
        m = rowmax16(m);
        m = fmaxf(m, __shfl_xor(m, 16));
        m = fmaxf(m, __shfl_xor(m, 32));
        float e0 = __expf(lg0 - m), e1 = __expf(lg1 - m);
        float zz = e0 + e1;
        zz = rowsum16(zz);
        zz += __shfl_xor(zz, 16);
        zz += __shfl_xor(zz, 32);
        float inv = 1.0f / zz;
        probs[r0] = e0 * inv;
        probs[r1] = e1 * inv;
      } else {
        lg0 += scl[0] * d0;            // rows 0..63   = routing a0
        lg1 += scl[1] * d1;            // rows 64..127 = routing a1
        float m0 = rowmax16(lg0), m1 = rowmax16(lg1);
        m0 = fmaxf(m0, __shfl_xor(m0, 16));
        m0 = fmaxf(m0, __shfl_xor(m0, 32));
        m1 = fmaxf(m1, __shfl_xor(m1, 16));
        m1 = fmaxf(m1, __shfl_xor(m1, 32));
        float e0 = __expf(lg0 - m0), e1 = __expf(lg1 - m1);
        float z0 = rowsum16(e0), z1 = rowsum16(e1);
        z0 += __shfl_xor(z0, 16);
        z0 += __shfl_xor(z0, 32);
        z1 += __shfl_xor(z1, 16);
        z1 += __shfl_xor(z1, 32);
        probs[r0] = e0 / z0;
        probs[r1] = e1 / z1;
      }
      asm volatile("s_waitcnt lgkmcnt(0)" ::: "memory");  // own writes land before next-iter reads
    }
  }

  // ---- epilogue. stage1 -> split out1[a][kk][e]; stage2 -> fp32 out[kk][a][e] ----
  // Both hi-halves hold identical v (s was xor32-reduced); lanes 0-31 write.
  if (hi == 0) {
#pragma unroll
    for (int sg = 0; sg < SEG; ++sg) {
      const int ag = ab * SEG + sg;      // global a
      if (stage == 1) {
        size_t ob = ((size_t)ag * KN + kk) * 256;
#pragma unroll
        for (int ct = 0; ct < 2; ++ct) {
          int e = eg * 64 + ct * 32 + l31;
          u32 hb = bf16_rne(v[sg][ct]);
          u32 lb = bf16_rne(v[sg][ct] - bf16_val(hb));
          o1hi[ob + e] = (u16)hb;
          o1lo[ob + e] = (u16)lb;
        }
      } else {
        size_t ob = ((size_t)kk * 64 + ag) * 256;
#pragma unroll
        for (int ct = 0; ct < 2; ++ct) {
          int e = eg * 64 + ct * 32 + l31;
          outp[ob + e] = v[sg][ct];
        }
      }
    }
  }
}

extern "C" void kernel_launch(void* const* d_in, const int* in_sizes, int n_in,
                              void* d_out, int out_size, void* d_ws, size_t ws_size,
                              hipStream_t stream) {
  const float* x  = (const float*)d_in[0];   // [64][128][256]
  const float* w1 = (const float*)d_in[1];   // [64][256][256]
  const float* wc = (const float*)d_in[2];   // [32][256][256]
  float* out = (float*)d_out;                // [32][64][256]

  char* ws = (char*)d_ws;
  u16* w1hi = (u16*)(ws);                    // 8 MB
  u16* w1lo = (u16*)(ws + (8u << 20));       // 8 MB
  u16* wchi = (u16*)(ws + (16u << 20));      // 4 MB
  u16* wclo = (u16*)(ws + (20u << 20));      // 4 MB
  u16* xhi  = (u16*)(ws + (24u << 20));      // 4 MB
  u16* xlo  = (u16*)(ws + (28u << 20));      // 4 MB
  u16* o1hi = (u16*)(ws + (32u << 20));      // 2 MB
  u16* o1lo = (u16*)(ws + (34u << 20));      // 2 MB

  split_arr<<<2048, 256, 0, stream>>>(x, xhi, xlo, 524288);
  split_transpose256<<<dim3(8, 8, 64), dim3(32, 8), 0, stream>>>(w1, w1hi, w1lo);
  split_transpose256<<<dim3(8, 8, 32), dim3(32, 8), 0, stream>>>(wc, wchi, wclo);
  // stage 1: 64 kk x 64 a-blocks (M=128 = 1 routing of R=128), 2 blocks/CU (reg-capped)
  caps_route<128><<<64 * 64, 256, 0, stream>>>(xhi, xlo, w1hi, w1lo, o1hi, o1lo, nullptr, 64, 1);
  // stage 2: 32 kk x 32 a-blocks (M=128 = 2 routings of R=64), 2 blocks/CU
  caps_route<64><<<32 * 32, 256, 0, stream>>>(o1hi, o1lo, wchi, wclo, nullptr, nullptr, out, 32, 2);
}